// Round 1
// baseline (1676.153 us; speedup 1.0000x reference)
//
#include <hip/hip_runtime.h>
#include <math.h>

#define HW 256
#define NPIX (HW*HW)            // 65536
#define TOT (2*4*NPIX)          // 524288 = B*C*H*W

__device__ __forceinline__ float sigmoidf_(float v) { return 1.f / (1.f + expf(-v)); }

// ---------------------------------------------------------------- K0: gfeat = mean over H,W
__global__ __launch_bounds__(256) void k_gfeat(const float* __restrict__ x, float* __restrict__ gfeat) {
    int bc = blockIdx.x;                       // 0..7 = b*4+c
    const float* p = x + (size_t)bc * NPIX;
    float s = 0.f;
    for (int i = threadIdx.x; i < NPIX; i += 256) s += p[i];
    for (int off = 32; off; off >>= 1) s += __shfl_down(s, off);
    __shared__ float ls[4];
    if ((threadIdx.x & 63) == 0) ls[threadIdx.x >> 6] = s;
    __syncthreads();
    if (threadIdx.x == 0) gfeat[bc] = (ls[0] + ls[1] + ls[2] + ls[3]) / (float)NPIX;
}

// ---------------------------------------------------------------- K2: input gating
__global__ __launch_bounds__(256) void k_gate(const float* __restrict__ x,
        const float* __restrict__ gfeat, const float* __restrict__ fc_w,
        const float* __restrict__ fc_b, const float* __restrict__ mw,
        float* __restrict__ state) {
    int idx = blockIdx.x * 256 + threadIdx.x;
    int c = (idx >> 16) & 3, b = idx >> 18;
    float a = fc_b[c];
#pragma unroll
    for (int j = 0; j < 4; ++j) a = fmaf(gfeat[b*4+j], fc_w[c*4+j], a);
    float s = sigmoidf_(a) * sigmoidf_(mw[c]);
    state[idx] = x[idx] * s;
}

// ---------------------------------------------------------------- fused conv branch: 4->128 relu -> 4
// out = conv2(relu(conv1(state))), 3x3, pad=D, dil=D.  16x16 output tile per block.
template<int D>
__global__ __launch_bounds__(256) void branch_conv(const float* __restrict__ state,
        const float* __restrict__ w1, const float* __restrict__ b1,
        const float* __restrict__ w2, const float* __restrict__ b2,
        float* __restrict__ out) {
    constexpr int T1 = 16 + 2*D;               // t1 tile (with conv2 halo)
    constexpr int S  = 16 + 4*D;               // state tile (with both halos)
    constexpr int OCC = 16;                    // output-channel chunk of conv1
    __shared__ float s_state[4][S][S];
    __shared__ float s_t1[OCC][T1][T1];

    const int b = blockIdx.z;
    const int ty0 = blockIdx.y * 16, tx0 = blockIdx.x * 16;
    const int tid = threadIdx.x;

    // load state tile (zero-padded at image boundary)
    for (int i = tid; i < 4 * S * S; i += 256) {
        int ic = i / (S*S); int r = i % (S*S); int sy = r / S; int sx = r % S;
        int Y = ty0 - 2*D + sy, X = tx0 - 2*D + sx;
        float v = 0.f;
        if (Y >= 0 && Y < HW && X >= 0 && X < HW)
            v = state[((b*4 + ic) * NPIX) + Y*HW + X];
        s_state[ic][sy][sx] = v;
    }

    const int iy = tid >> 4, ix = tid & 15;
    float acc[4] = { b2[0], b2[1], b2[2], b2[3] };

    for (int ch = 0; ch < 8; ++ch) {
        __syncthreads();                        // t1 reuse + (first iter) state-tile ready
        // phase A: conv1 + relu for a chunk of 16 channels over the T1xT1 halo tile
        for (int e = tid; e < T1*T1; e += 256) {
            int ly = e / T1, lx = e % T1;
            int Y = ty0 - D + ly, X = tx0 - D + lx;
            bool valid = (Y >= 0 && Y < HW && X >= 0 && X < HW);  // conv2 zero-pads t1 at IMAGE bounds
            float patch[36];
#pragma unroll
            for (int ic = 0; ic < 4; ++ic)
#pragma unroll
                for (int dy = 0; dy < 3; ++dy)
#pragma unroll
                    for (int dx = 0; dx < 3; ++dx)
                        patch[ic*9 + dy*3 + dx] = s_state[ic][ly + dy*D][lx + dx*D];
#pragma unroll
            for (int o = 0; o < OCC; ++o) {
                int oc = ch*OCC + o;
                const float* wr = &w1[oc*36];
                float a = b1[oc];
#pragma unroll
                for (int k = 0; k < 36; ++k) a = fmaf(patch[k], wr[k], a);
                s_t1[o][ly][lx] = valid ? fmaxf(a, 0.f) : 0.f;
            }
        }
        __syncthreads();
        // phase B: conv2 partial accumulation over this chunk; 1 thread = 1 out pixel
#pragma unroll
        for (int dy = 0; dy < 3; ++dy)
#pragma unroll
            for (int dx = 0; dx < 3; ++dx) {
#pragma unroll
                for (int icl = 0; icl < OCC; ++icl) {
                    float tv = s_t1[icl][iy + dy*D][ix + dx*D];
                    int ic = ch*OCC + icl;
#pragma unroll
                    for (int oc = 0; oc < 4; ++oc)
                        acc[oc] = fmaf(tv, w2[(oc*128 + ic)*9 + dy*3 + dx], acc[oc]);
                }
            }
    }
#pragma unroll
    for (int oc = 0; oc < 4; ++oc)
        out[((b*4 + oc) * NPIX) + (ty0 + iy)*HW + (tx0 + ix)] = acc[oc];
}

// ---------------------------------------------------------------- K5: sobel + boxsums + sim (unnorm) + per-(b,c) sim sum
__global__ __launch_bounds__(256) void k_sim(const float* __restrict__ state,
        float* __restrict__ sim, float* __restrict__ bs_state_o, float* __restrict__ sums) {
    const int bc = blockIdx.z;
    const int ty0 = blockIdx.y * 32, tx0 = blockIdx.x * 32;
    const float* sp = state + (size_t)bc * NPIX;
    __shared__ float st[38][38];
    __shared__ float gmt[36][36];
    __shared__ float rs_g[36][32], rs_g2[36][32], rs_s[36][32];
    const int tid = threadIdx.x;

    for (int i = tid; i < 38*38; i += 256) {
        int sy = i / 38, sx = i % 38;
        int Y = ty0 - 3 + sy, X = tx0 - 3 + sx;
        float v = 0.f;
        if (Y >= 0 && Y < HW && X >= 0 && X < HW) v = sp[Y*HW + X];
        st[sy][sx] = v;
    }
    __syncthreads();
    for (int i = tid; i < 36*36; i += 256) {
        int ly = i / 36, lx = i % 36;
        int Y = ty0 - 2 + ly, X = tx0 - 2 + lx;
        float g = 0.f;
        if (Y >= 0 && Y < HW && X >= 0 && X < HW) {   // boxsum zero-pads gm at IMAGE bounds
            float a00 = st[ly][lx],   a01 = st[ly][lx+1],   a02 = st[ly][lx+2];
            float a10 = st[ly+1][lx],                       a12 = st[ly+1][lx+2];
            float a20 = st[ly+2][lx], a21 = st[ly+2][lx+1], a22 = st[ly+2][lx+2];
            float gx = (a02 + 2.f*a12 + a22) - (a00 + 2.f*a10 + a20);
            float gy = (a20 + 2.f*a21 + a22) - (a00 + 2.f*a01 + a02);
            g = sqrtf(gx*gx + gy*gy);
        }
        gmt[ly][lx] = g;
    }
    __syncthreads();
    for (int i = tid; i < 36*32; i += 256) {
        int ly = i / 32, ix = i % 32;
        float sg = 0.f, sg2 = 0.f, ss = 0.f;
#pragma unroll
        for (int d = 0; d < 5; ++d) {
            float g = gmt[ly][ix + d];
            sg += g; sg2 += g*g;
            ss += st[ly + 1][ix + d + 1];
        }
        rs_g[ly][ix] = sg; rs_g2[ly][ix] = sg2; rs_s[ly][ix] = ss;
    }
    __syncthreads();
    float lsum = 0.f;
#pragma unroll
    for (int k = 0; k < 4; ++k) {
        int i = tid + k*256;
        int iy = i >> 5, ix = i & 31;
        float bg = 0.f, bg2 = 0.f, bs = 0.f;
#pragma unroll
        for (int d = 0; d < 5; ++d) { bg += rs_g[iy+d][ix]; bg2 += rs_g2[iy+d][ix]; bs += rs_s[iy+d][ix]; }
        float g = gmt[iy+2][ix+2];
        float dist = bg2 - 2.f*g*bg + 25.f*g*g;
        float sv = expf(-2.f * dist);
        int gi = bc*NPIX + (ty0+iy)*HW + (tx0+ix);
        sim[gi] = sv;
        bs_state_o[gi] = bs;
        lsum += sv;
    }
    for (int off = 32; off; off >>= 1) lsum += __shfl_down(lsum, off);
    __shared__ float ls[4];
    if ((tid & 63) == 0) ls[tid >> 6] = lsum;
    __syncthreads();
    if (tid == 0) atomicAdd(&sums[bc], ls[0] + ls[1] + ls[2] + ls[3]);
}

// ---------------------------------------------------------------- K6: combine + DynamicConv
__global__ __launch_bounds__(256) void k_combine(const float* __restrict__ state,
        const float* __restrict__ sim, const float* __restrict__ bs_state,
        const float* __restrict__ upd, const float* __restrict__ nbr,
        const float* __restrict__ dc_w, const float* __restrict__ dc_b,
        const float* __restrict__ sums, float* __restrict__ state_out) {
    int idx = blockIdx.x * 256 + threadIdx.x;
    int x = idx & 255, y = (idx >> 8) & 255, c = (idx >> 16) & 3, b = idx >> 18;
    float hf = dc_b[c];
#pragma unroll
    for (int ic = 0; ic < 4; ++ic) {
        const float* sp = state + ((b*4 + ic) * NPIX);
#pragma unroll
        for (int dy = -1; dy <= 1; ++dy)
#pragma unroll
            for (int dx = -1; dx <= 1; ++dx) {
                int Y = y + dy, X = x + dx;
                float v = (Y >= 0 && Y < HW && X >= 0 && X < HW) ? sp[Y*HW + X] : 0.f;
                hf = fmaf(v, dc_w[((c*4 + ic)*3 + dy + 1)*3 + dx + 1], hf);
            }
    }
    float w = sim[idx] / (sums[b*4 + c] + 1e-8f) * bs_state[idx];
    state_out[idx] = w + upd[idx] + nbr[idx] + hf;
}

// ---------------------------------------------------------------- K7: epilogue (branches + sel + out + loss)
__global__ __launch_bounds__(256) void k_epilogue(const float* __restrict__ state,
        const int* __restrict__ tm, const float* __restrict__ dc_w, const float* __restrict__ dc_b,
        float* __restrict__ out, float* __restrict__ loss_acc) {
    int idx = blockIdx.x * 256 + threadIdx.x;
    int x = idx & 255, y = (idx >> 8) & 255, c = (idx >> 16) & 3, b = idx >> 18;
    const float* sp = state + ((b*4 + c) * NPIX);
    // sobel
    float a00, a01, a02, a10, a12, a20, a21, a22;
    {
        auto rd = [&](int Y, int X) -> float {
            return (Y >= 0 && Y < HW && X >= 0 && X < HW) ? sp[Y*HW + X] : 0.f;
        };
        a00 = rd(y-1,x-1); a01 = rd(y-1,x); a02 = rd(y-1,x+1);
        a10 = rd(y,  x-1);                  a12 = rd(y,  x+1);
        a20 = rd(y+1,x-1); a21 = rd(y+1,x); a22 = rd(y+1,x+1);
    }
    float gx = (a02 + 2.f*a12 + a22) - (a00 + 2.f*a10 + a20);
    float gy = (a20 + 2.f*a21 + a22) - (a00 + 2.f*a01 + a02);
    float gm = sqrtf(gx*gx + gy*gy);
    // dc conv
    float hfl = dc_b[c];
#pragma unroll
    for (int ic = 0; ic < 4; ++ic) {
        const float* sp2 = state + ((b*4 + ic) * NPIX);
#pragma unroll
        for (int dy = -1; dy <= 1; ++dy)
#pragma unroll
            for (int dx = -1; dx <= 1; ++dx) {
                int Y = y + dy, X = x + dx;
                float v = (Y >= 0 && Y < HW && X >= 0 && X < HW) ? sp2[Y*HW + X] : 0.f;
                hfl = fmaf(v, dc_w[((c*4 + ic)*3 + dy + 1)*3 + dx + 1], hfl);
            }
    }
    float hf = sigmoidf_(hfl);
    float sgm = sigmoidf_(gm);
    int t = tm[b];
    float pos, neg;
    if (t == 0)      { pos = hf;                      neg = 1.f - sgm; }
    else if (t == 1) { pos = sgm;                     neg = 1.f - hf; }
    else if (t == 2) { pos = hf * sgm;                neg = 1.f - hf * sgm; }
    else             { float q = sigmoidf_(gm * hf);  pos = q;  neg = 1.f - q; }
    pos = fminf(fmaxf(pos, 0.f), 1.f);
    neg = fminf(fmaxf(neg, 0.f), 1.f);
    float ep = expf(pos), en = expf(neg);
    float sel = ep / (ep + en + 1e-8f);
    out[idx] = sp[y*HW + x] * sel;
    float lt = sel * neg + (1.f - sel) * pos;
    for (int off = 32; off; off >>= 1) lt += __shfl_down(lt, off);
    __shared__ float ls[4];
    if ((threadIdx.x & 63) == 0) ls[threadIdx.x >> 6] = lt;
    __syncthreads();
    if (threadIdx.x == 0) atomicAdd(loss_acc, ls[0] + ls[1] + ls[2] + ls[3]);
}

__global__ void k_write_loss(const float* __restrict__ loss, float* __restrict__ out) {
    out[TOT] = loss[0] / (float)TOT;
}

// ---------------------------------------------------------------- host
extern "C" void kernel_launch(void* const* d_in, const int* in_sizes, int n_in,
                              void* d_out, int out_size, void* d_ws, size_t ws_size,
                              hipStream_t stream) {
    const float* x     = (const float*)d_in[0];
    const int*   tm    = (const int*)  d_in[1];
    const float* fc_w  = (const float*)d_in[2];
    const float* fc_b  = (const float*)d_in[3];
    const float* mw    = (const float*)d_in[4];
    const float* su_w1 = (const float*)d_in[5];
    const float* su_b1 = (const float*)d_in[6];
    const float* su_w2 = (const float*)d_in[7];
    const float* su_b2 = (const float*)d_in[8];
    const float* nu_w1 = (const float*)d_in[9];
    const float* nu_b1 = (const float*)d_in[10];
    const float* nu_w2 = (const float*)d_in[11];
    const float* nu_b2 = (const float*)d_in[12];
    const float* dc_w  = (const float*)d_in[13];
    const float* dc_b  = (const float*)d_in[14];

    float* ws      = (float*)d_ws;
    float* state_a = ws;
    float* state_b = ws + (size_t)TOT;
    float* upd     = ws + (size_t)2*TOT;
    float* nbr     = ws + (size_t)3*TOT;
    float* sim     = ws + (size_t)4*TOT;
    float* bs      = ws + (size_t)5*TOT;
    float* gfeat   = ws + (size_t)6*TOT;
    float* sums    = gfeat + 8;      // 3 iters x 8
    float* loss    = sums + 24;

    hipMemsetAsync(sums, 0, 25 * sizeof(float), stream);
    k_gfeat<<<8, 256, 0, stream>>>(x, gfeat);
    k_gate<<<TOT/256, 256, 0, stream>>>(x, gfeat, fc_w, fc_b, mw, state_a);

    float* cur = state_a; float* nxt = state_b;
    dim3 g16(16, 16, 2);
    dim3 g32(8, 8, 8);
    for (int it = 0; it < 3; ++it) {
        branch_conv<1><<<g16, 256, 0, stream>>>(cur, su_w1, su_b1, su_w2, su_b2, upd);
        branch_conv<2><<<g16, 256, 0, stream>>>(cur, nu_w1, nu_b1, nu_w2, nu_b2, nbr);
        k_sim<<<g32, 256, 0, stream>>>(cur, sim, bs, sums + it*8);
        k_combine<<<TOT/256, 256, 0, stream>>>(cur, sim, bs, upd, nbr, dc_w, dc_b, sums + it*8, nxt);
        float* t = cur; cur = nxt; nxt = t;
    }
    k_epilogue<<<TOT/256, 256, 0, stream>>>(cur, tm, dc_w, dc_b, (float*)d_out, loss);
    k_write_loss<<<1, 1, 0, stream>>>(loss, (float*)d_out);
}

// Round 2
// 896.292 us; speedup vs baseline: 1.8701x; 1.8701x over previous
//
#include <hip/hip_runtime.h>
#include <math.h>

#define HW 256
#define NPIX (HW*HW)            // 65536
#define TOT (2*4*NPIX)          // 524288 = B*C*H*W

__device__ __forceinline__ float sigmoidf_(float v) { return 1.f / (1.f + expf(-v)); }

// ---------------------------------------------------------------- K0: gfeat = mean over H,W
__global__ __launch_bounds__(256) void k_gfeat(const float* __restrict__ x, float* __restrict__ gfeat) {
    int bc = blockIdx.x;                       // 0..7 = b*4+c
    const float* p = x + (size_t)bc * NPIX;
    float s = 0.f;
    for (int i = threadIdx.x; i < NPIX; i += 256) s += p[i];
    for (int off = 32; off; off >>= 1) s += __shfl_down(s, off);
    __shared__ float ls[4];
    if ((threadIdx.x & 63) == 0) ls[threadIdx.x >> 6] = s;
    __syncthreads();
    if (threadIdx.x == 0) gfeat[bc] = (ls[0] + ls[1] + ls[2] + ls[3]) / (float)NPIX;
}

// ---------------------------------------------------------------- K2: input gating
__global__ __launch_bounds__(256) void k_gate(const float* __restrict__ x,
        const float* __restrict__ gfeat, const float* __restrict__ fc_w,
        const float* __restrict__ fc_b, const float* __restrict__ mw,
        float* __restrict__ state) {
    int idx = blockIdx.x * 256 + threadIdx.x;
    int c = (idx >> 16) & 3, b = idx >> 18;
    float a = fc_b[c];
#pragma unroll
    for (int j = 0; j < 4; ++j) a = fmaf(gfeat[b*4+j], fc_w[c*4+j], a);
    float s = sigmoidf_(a) * sigmoidf_(mw[c]);
    state[idx] = x[idx] * s;
}

// ---------------------------------------------------------------- fused conv branch: 4->128 relu -> 4
// Channel-SPLIT across blocks: blockIdx.z = img*2 + half; half h covers conv1 oc
// (= conv2 ic) in [64h, 64h+64). Each half writes a partial-sum buffer at
// out + half*TOT; k_combine adds both halves. Doubles grid -> 4 blocks/CU.
template<int D>
__global__ __launch_bounds__(256, 4) void branch_conv(const float* __restrict__ state,
        const float* __restrict__ w1, const float* __restrict__ b1,
        const float* __restrict__ w2, const float* __restrict__ b2,
        float* __restrict__ out) {
    constexpr int T1 = 16 + 2*D;               // t1 tile (with conv2 halo)
    constexpr int TP = T1 + 2;                 // t1 row pitch (bank stagger)
    constexpr int S  = 16 + 4*D;               // state tile (both halos)
    constexpr int SP = S + 1;
    __shared__ float s_state[4][S][SP];
    __shared__ float s_t1[16][T1][TP];         // 16-channel chunk

    const int half = blockIdx.z & 1;
    const int b    = blockIdx.z >> 1;
    const int ty0 = blockIdx.y * 16, tx0 = blockIdx.x * 16;
    const int tid = threadIdx.x;

    // load state tile (zero-padded at image boundary)
    for (int i = tid; i < 4 * S * S; i += 256) {
        int ic = i / (S*S); int r = i % (S*S); int sy = r / S; int sx = r % S;
        int Y = ty0 - 2*D + sy, X = tx0 - 2*D + sx;
        float v = 0.f;
        if (Y >= 0 && Y < HW && X >= 0 && X < HW)
            v = state[((b*4 + ic) * NPIX) + Y*HW + X];
        s_state[ic][sy][sx] = v;
    }

    const int iy = tid >> 4, ix = tid & 15;
    float acc[4];
#pragma unroll
    for (int oc = 0; oc < 4; ++oc) acc[oc] = (half == 0) ? b2[oc] : 0.f;

    for (int ch = 0; ch < 4; ++ch) {           // 4 chunks x 16 channels = 64 (this half)
        __syncthreads();                        // t1 buffer free / state tile ready
        // phase A: conv1+relu for chunk channels over T1xT1 halo grid
        for (int e = tid; e < T1*T1; e += 256) {
            int ly = e / T1, lx = e - ly*T1;
            int Y = ty0 - D + ly, X = tx0 - D + lx;
            bool valid = (Y >= 0 && Y < HW && X >= 0 && X < HW);  // conv2 zero-pads at IMAGE bounds
            float patch[36];
#pragma unroll
            for (int ic = 0; ic < 4; ++ic)
#pragma unroll
                for (int dy = 0; dy < 3; ++dy)
#pragma unroll
                    for (int dx = 0; dx < 3; ++dx)
                        patch[ic*9 + dy*3 + dx] = s_state[ic][ly + dy*D][lx + dx*D];
#pragma unroll
            for (int o = 0; o < 16; ++o) {
                int goc = half*64 + ch*16 + o;          // uniform -> weights via s_load
                const float* wr = &w1[goc*36];
                float a = b1[goc];
#pragma unroll
                for (int k = 0; k < 36; ++k) a = fmaf(patch[k], wr[k], a);
                s_t1[o][ly][lx] = valid ? fmaxf(a, 0.f) : 0.f;
            }
        }
        __syncthreads();
        // phase B: conv2 partial accumulation; 1 thread = 1 out pixel
#pragma unroll
        for (int icl = 0; icl < 16; ++icl) {
            float t[9];
#pragma unroll
            for (int dy = 0; dy < 3; ++dy)
#pragma unroll
                for (int dx = 0; dx < 3; ++dx)
                    t[dy*3+dx] = s_t1[icl][iy + dy*D][ix + dx*D];
            int gic = half*64 + ch*16 + icl;            // uniform -> s_load rows
#pragma unroll
            for (int oc = 0; oc < 4; ++oc) {
                const float* wr = &w2[(oc*128 + gic)*9];
#pragma unroll
                for (int k = 0; k < 9; ++k) acc[oc] = fmaf(t[k], wr[k], acc[oc]);
            }
        }
    }
    float* op = out + (size_t)half * TOT;
#pragma unroll
    for (int oc = 0; oc < 4; ++oc)
        op[((b*4 + oc) * NPIX) + (ty0 + iy)*HW + (tx0 + ix)] = acc[oc];
}

// ---------------------------------------------------------------- K5: sobel + boxsums + sim (unnorm) + per-(b,c) sim sum
__global__ __launch_bounds__(256) void k_sim(const float* __restrict__ state,
        float* __restrict__ sim, float* __restrict__ bs_state_o, float* __restrict__ sums) {
    const int bc = blockIdx.z;
    const int ty0 = blockIdx.y * 32, tx0 = blockIdx.x * 32;
    const float* sp = state + (size_t)bc * NPIX;
    __shared__ float st[38][38];
    __shared__ float gmt[36][36];
    __shared__ float rs_g[36][32], rs_g2[36][32], rs_s[36][32];
    const int tid = threadIdx.x;

    for (int i = tid; i < 38*38; i += 256) {
        int sy = i / 38, sx = i % 38;
        int Y = ty0 - 3 + sy, X = tx0 - 3 + sx;
        float v = 0.f;
        if (Y >= 0 && Y < HW && X >= 0 && X < HW) v = sp[Y*HW + X];
        st[sy][sx] = v;
    }
    __syncthreads();
    for (int i = tid; i < 36*36; i += 256) {
        int ly = i / 36, lx = i % 36;
        int Y = ty0 - 2 + ly, X = tx0 - 2 + lx;
        float g = 0.f;
        if (Y >= 0 && Y < HW && X >= 0 && X < HW) {   // boxsum zero-pads gm at IMAGE bounds
            float a00 = st[ly][lx],   a01 = st[ly][lx+1],   a02 = st[ly][lx+2];
            float a10 = st[ly+1][lx],                       a12 = st[ly+1][lx+2];
            float a20 = st[ly+2][lx], a21 = st[ly+2][lx+1], a22 = st[ly+2][lx+2];
            float gx = (a02 + 2.f*a12 + a22) - (a00 + 2.f*a10 + a20);
            float gy = (a20 + 2.f*a21 + a22) - (a00 + 2.f*a01 + a02);
            g = sqrtf(gx*gx + gy*gy);
        }
        gmt[ly][lx] = g;
    }
    __syncthreads();
    for (int i = tid; i < 36*32; i += 256) {
        int ly = i / 32, ix = i % 32;
        float sg = 0.f, sg2 = 0.f, ss = 0.f;
#pragma unroll
        for (int d = 0; d < 5; ++d) {
            float g = gmt[ly][ix + d];
            sg += g; sg2 += g*g;
            ss += st[ly + 1][ix + d + 1];
        }
        rs_g[ly][ix] = sg; rs_g2[ly][ix] = sg2; rs_s[ly][ix] = ss;
    }
    __syncthreads();
    float lsum = 0.f;
#pragma unroll
    for (int k = 0; k < 4; ++k) {
        int i = tid + k*256;
        int iy = i >> 5, ix = i & 31;
        float bg = 0.f, bg2 = 0.f, bs = 0.f;
#pragma unroll
        for (int d = 0; d < 5; ++d) { bg += rs_g[iy+d][ix]; bg2 += rs_g2[iy+d][ix]; bs += rs_s[iy+d][ix]; }
        float g = gmt[iy+2][ix+2];
        float dist = bg2 - 2.f*g*bg + 25.f*g*g;
        float sv = expf(-2.f * dist);
        int gi = bc*NPIX + (ty0+iy)*HW + (tx0+ix);
        sim[gi] = sv;
        bs_state_o[gi] = bs;
        lsum += sv;
    }
    for (int off = 32; off; off >>= 1) lsum += __shfl_down(lsum, off);
    __shared__ float ls[4];
    if ((tid & 63) == 0) ls[tid >> 6] = lsum;
    __syncthreads();
    if (tid == 0) atomicAdd(&sums[bc], ls[0] + ls[1] + ls[2] + ls[3]);
}

// ---------------------------------------------------------------- K6: combine + DynamicConv
// upd/nbr each have TWO half-buffers (channel-split partials) at +0 and +TOT.
__global__ __launch_bounds__(256) void k_combine(const float* __restrict__ state,
        const float* __restrict__ sim, const float* __restrict__ bs_state,
        const float* __restrict__ upd, const float* __restrict__ nbr,
        const float* __restrict__ dc_w, const float* __restrict__ dc_b,
        const float* __restrict__ sums, float* __restrict__ state_out) {
    int idx = blockIdx.x * 256 + threadIdx.x;
    int x = idx & 255, y = (idx >> 8) & 255, c = (idx >> 16) & 3, b = idx >> 18;
    float hf = dc_b[c];
#pragma unroll
    for (int ic = 0; ic < 4; ++ic) {
        const float* sp = state + ((b*4 + ic) * NPIX);
#pragma unroll
        for (int dy = -1; dy <= 1; ++dy)
#pragma unroll
            for (int dx = -1; dx <= 1; ++dx) {
                int Y = y + dy, X = x + dx;
                float v = (Y >= 0 && Y < HW && X >= 0 && X < HW) ? sp[Y*HW + X] : 0.f;
                hf = fmaf(v, dc_w[((c*4 + ic)*3 + dy + 1)*3 + dx + 1], hf);
            }
    }
    float w = sim[idx] / (sums[b*4 + c] + 1e-8f) * bs_state[idx];
    state_out[idx] = w + (upd[idx] + upd[idx + TOT]) + (nbr[idx] + nbr[idx + TOT]) + hf;
}

// ---------------------------------------------------------------- K7: epilogue (branches + sel + out + loss)
__global__ __launch_bounds__(256) void k_epilogue(const float* __restrict__ state,
        const int* __restrict__ tm, const float* __restrict__ dc_w, const float* __restrict__ dc_b,
        float* __restrict__ out, float* __restrict__ loss_acc) {
    int idx = blockIdx.x * 256 + threadIdx.x;
    int x = idx & 255, y = (idx >> 8) & 255, c = (idx >> 16) & 3, b = idx >> 18;
    const float* sp = state + ((b*4 + c) * NPIX);
    float a00, a01, a02, a10, a12, a20, a21, a22;
    {
        auto rd = [&](int Y, int X) -> float {
            return (Y >= 0 && Y < HW && X >= 0 && X < HW) ? sp[Y*HW + X] : 0.f;
        };
        a00 = rd(y-1,x-1); a01 = rd(y-1,x); a02 = rd(y-1,x+1);
        a10 = rd(y,  x-1);                  a12 = rd(y,  x+1);
        a20 = rd(y+1,x-1); a21 = rd(y+1,x); a22 = rd(y+1,x+1);
    }
    float gx = (a02 + 2.f*a12 + a22) - (a00 + 2.f*a10 + a20);
    float gy = (a20 + 2.f*a21 + a22) - (a00 + 2.f*a01 + a02);
    float gm = sqrtf(gx*gx + gy*gy);
    float hfl = dc_b[c];
#pragma unroll
    for (int ic = 0; ic < 4; ++ic) {
        const float* sp2 = state + ((b*4 + ic) * NPIX);
#pragma unroll
        for (int dy = -1; dy <= 1; ++dy)
#pragma unroll
            for (int dx = -1; dx <= 1; ++dx) {
                int Y = y + dy, X = x + dx;
                float v = (Y >= 0 && Y < HW && X >= 0 && X < HW) ? sp2[Y*HW + X] : 0.f;
                hfl = fmaf(v, dc_w[((c*4 + ic)*3 + dy + 1)*3 + dx + 1], hfl);
            }
    }
    float hf = sigmoidf_(hfl);
    float sgm = sigmoidf_(gm);
    int t = tm[b];
    float pos, neg;
    if (t == 0)      { pos = hf;                      neg = 1.f - sgm; }
    else if (t == 1) { pos = sgm;                     neg = 1.f - hf; }
    else if (t == 2) { pos = hf * sgm;                neg = 1.f - hf * sgm; }
    else             { float q = sigmoidf_(gm * hf);  pos = q;  neg = 1.f - q; }
    pos = fminf(fmaxf(pos, 0.f), 1.f);
    neg = fminf(fmaxf(neg, 0.f), 1.f);
    float ep = expf(pos), en = expf(neg);
    float sel = ep / (ep + en + 1e-8f);
    out[idx] = sp[y*HW + x] * sel;
    float lt = sel * neg + (1.f - sel) * pos;
    for (int off = 32; off; off >>= 1) lt += __shfl_down(lt, off);
    __shared__ float ls[4];
    if ((threadIdx.x & 63) == 0) ls[threadIdx.x >> 6] = lt;
    __syncthreads();
    if (threadIdx.x == 0) atomicAdd(loss_acc, ls[0] + ls[1] + ls[2] + ls[3]);
}

__global__ void k_write_loss(const float* __restrict__ loss, float* __restrict__ out) {
    out[TOT] = loss[0] / (float)TOT;
}

// ---------------------------------------------------------------- host
extern "C" void kernel_launch(void* const* d_in, const int* in_sizes, int n_in,
                              void* d_out, int out_size, void* d_ws, size_t ws_size,
                              hipStream_t stream) {
    const float* x     = (const float*)d_in[0];
    const int*   tm    = (const int*)  d_in[1];
    const float* fc_w  = (const float*)d_in[2];
    const float* fc_b  = (const float*)d_in[3];
    const float* mw    = (const float*)d_in[4];
    const float* su_w1 = (const float*)d_in[5];
    const float* su_b1 = (const float*)d_in[6];
    const float* su_w2 = (const float*)d_in[7];
    const float* su_b2 = (const float*)d_in[8];
    const float* nu_w1 = (const float*)d_in[9];
    const float* nu_b1 = (const float*)d_in[10];
    const float* nu_w2 = (const float*)d_in[11];
    const float* nu_b2 = (const float*)d_in[12];
    const float* dc_w  = (const float*)d_in[13];
    const float* dc_b  = (const float*)d_in[14];

    float* ws      = (float*)d_ws;
    float* state_a = ws;
    float* state_b = ws + (size_t)TOT;
    float* upd     = ws + (size_t)2*TOT;   // halves at +0, +TOT
    float* nbr     = ws + (size_t)4*TOT;   // halves at +0, +TOT
    float* sim     = ws + (size_t)6*TOT;
    float* bs      = ws + (size_t)7*TOT;
    float* gfeat   = ws + (size_t)8*TOT;
    float* sums    = gfeat + 8;            // 3 iters x 8
    float* loss    = sums + 24;

    hipMemsetAsync(sums, 0, 25 * sizeof(float), stream);
    k_gfeat<<<8, 256, 0, stream>>>(x, gfeat);
    k_gate<<<TOT/256, 256, 0, stream>>>(x, gfeat, fc_w, fc_b, mw, state_a);

    float* cur = state_a; float* nxt = state_b;
    dim3 gbc(16, 16, 4);                   // x-tiles, y-tiles, img*2+half
    dim3 g32(8, 8, 8);
    for (int it = 0; it < 3; ++it) {
        branch_conv<1><<<gbc, 256, 0, stream>>>(cur, su_w1, su_b1, su_w2, su_b2, upd);
        branch_conv<2><<<gbc, 256, 0, stream>>>(cur, nu_w1, nu_b1, nu_w2, nu_b2, nbr);
        k_sim<<<g32, 256, 0, stream>>>(cur, sim, bs, sums + it*8);
        k_combine<<<TOT/256, 256, 0, stream>>>(cur, sim, bs, upd, nbr, dc_w, dc_b, sums + it*8, nxt);
        float* t = cur; cur = nxt; nxt = t;
    }
    k_epilogue<<<TOT/256, 256, 0, stream>>>(cur, tm, dc_w, dc_b, (float*)d_out, loss);
    k_write_loss<<<1, 1, 0, stream>>>(loss, (float*)d_out);
}